// Round 9
// baseline (307.606 us; speedup 1.0000x reference)
//
#include <hip/hip_runtime.h>

typedef __bf16 bf16x8 __attribute__((ext_vector_type(8)));
typedef float f32x4 __attribute__((ext_vector_type(4)));

// Async global->LDS, 16B per lane. Global side: PER-LANE addresses (gather ok).
// LDS side: wave-uniform base + lane*16 (no padding within a call's 1 KB).
__device__ inline void gload16(const __bf16* g, __bf16* l) {
  __builtin_amdgcn_global_load_lds(
      (const __attribute__((address_space(1))) unsigned int*)g,
      (__attribute__((address_space(3))) unsigned int*)l, 16, 0, 0);
}

// ---------------------------------------------------------------------------
// Prep: fp32 -> bf16 elementwise (x). 8 elems/thread.
// ---------------------------------------------------------------------------
__global__ __launch_bounds__(256) void conv_bf16(
    const float* __restrict__ in, __bf16* __restrict__ out)
{
  size_t i = ((size_t)blockIdx.x * 256 + threadIdx.x) * 8;
  float4 a = *(const float4*)&in[i];
  float4 b = *(const float4*)&in[i + 4];
  bf16x8 h;
  h[0] = (__bf16)a.x; h[1] = (__bf16)a.y; h[2] = (__bf16)a.z; h[3] = (__bf16)a.w;
  h[4] = (__bf16)b.x; h[5] = (__bf16)b.y; h[6] = (__bf16)b.z; h[7] = (__bf16)b.w;
  *(bf16x8*)&out[i] = h;
}

// ---------------------------------------------------------------------------
// Prep: W fp32 [Kd][Nd] -> WT bf16 [Nd][Kd]. 64x64 LDS tile.
// ---------------------------------------------------------------------------
__global__ __launch_bounds__(256) void transpose_w(
    const float* __restrict__ W, __bf16* __restrict__ WT, int Kd, int Nd)
{
  __shared__ __bf16 Ts[64 * 72];
  const int tid = threadIdx.x;
  const int c0 = blockIdx.x * 64, r0 = blockIdx.y * 64;
#pragma unroll
  for (int i = 0; i < 4; i++) {
    int row = (tid >> 4) + i * 16, cv = (tid & 15) * 4;
    float4 w = *(const float4*)&W[(size_t)(r0 + row) * Nd + c0 + cv];
    Ts[(cv + 0) * 72 + row] = (__bf16)w.x;
    Ts[(cv + 1) * 72 + row] = (__bf16)w.y;
    Ts[(cv + 2) * 72 + row] = (__bf16)w.z;
    Ts[(cv + 3) * 72 + row] = (__bf16)w.w;
  }
  __syncthreads();
#pragma unroll
  for (int i = 0; i < 4; i++) {
    int n = (tid >> 4) + i * 16, kseg = (tid & 15) * 4;
    *(uint2*)&WT[(size_t)(c0 + n) * Kd + r0 + kseg] = *(uint2*)&Ts[n * 72 + kseg];
  }
}

// ---------------------------------------------------------------------------
// Prep: v bf16 [B*T][128] -> vT bf16 [B][128][T]. 64x64 tiles.
// ---------------------------------------------------------------------------
__global__ __launch_bounds__(256) void transpose_v(
    const __bf16* __restrict__ V, __bf16* __restrict__ VT)
{
  __shared__ __bf16 Ts[64 * 72];
  const int tid = threadIdx.x;
  const int t0 = blockIdx.x * 64, d0 = blockIdx.y * 64, bz = blockIdx.z;
#pragma unroll
  for (int i = 0; i < 4; i++) {
    int tr = (tid >> 4) + i * 16, dc = (tid & 15) * 4;
    union { uint2 u; __bf16 h[4]; } v;
    v.u = *(const uint2*)&V[(size_t)(bz * 2048 + t0 + tr) * 128 + d0 + dc];
    Ts[(dc + 0) * 72 + tr] = v.h[0];
    Ts[(dc + 1) * 72 + tr] = v.h[1];
    Ts[(dc + 2) * 72 + tr] = v.h[2];
    Ts[(dc + 3) * 72 + tr] = v.h[3];
  }
  __syncthreads();
#pragma unroll
  for (int i = 0; i < 4; i++) {
    int d = (tid >> 4) + i * 16, ts = (tid & 15) * 4;
    *(uint2*)&VT[(size_t)bz * 128 * 2048 + (size_t)(d0 + d) * 2048 + t0 + ts] =
        *(uint2*)&Ts[d * 72 + ts];
  }
}

// ---------------------------------------------------------------------------
// Fused q/k/v projection GEMM, BK=64 with 2x 32-col LDS panels (each panel
// keeps the proven [row][32] fragment layout). 32 MFMAs between barriers.
// ---------------------------------------------------------------------------
__global__ __launch_bounds__(256) void gemm_qkv(
    const __bf16* __restrict__ A, const __bf16* __restrict__ WqT,
    const __bf16* __restrict__ WkT, const __bf16* __restrict__ WvT,
    __bf16* __restrict__ Cq, __bf16* __restrict__ Ck, __bf16* __restrict__ Cv)
{
  __shared__ __align__(16) __bf16 Apan[2][128 * 32];
  __shared__ __align__(16) __bf16 Bpan[2][128 * 32];
  const int tid = threadIdx.x, wave = tid >> 6, lane = tid & 63;
  const int quad = lane >> 4, l16 = lane & 15;
  const int nb = blockIdx.x, m0 = blockIdx.y * 128;
  const __bf16* BT; __bf16* C; int ldC, c0;
  if (nb < 16)       { BT = WqT + (size_t)nb * 128 * 2048; C = Cq; ldC = 2048; c0 = nb * 128; }
  else if (nb == 16) { BT = WkT; C = Ck; ldC = 128; c0 = 0; }
  else               { BT = WvT; C = Cv; ldC = 128; c0 = 0; }
  const int wm = (wave >> 1) * 64, wn = (wave & 1) * 64;
  const int srow = lane >> 2, sseg = (lane & 3) * 8;

  f32x4 acc[4][4];
#pragma unroll
  for (int i = 0; i < 4; i++)
#pragma unroll
    for (int j = 0; j < 4; j++) acc[i][j] = (f32x4){0.f, 0.f, 0.f, 0.f};

  for (int k0 = 0; k0 < 2048; k0 += 64) {
    __syncthreads();
#pragma unroll
    for (int c = 0; c < 4; c++) {
      int idx = wave * 4 + c;            // 0..15
      int p = idx >> 3, rg = (idx & 7) * 16;
      gload16(&A[(size_t)(m0 + rg + srow) * 2048 + k0 + p * 32 + sseg], &Apan[p][rg * 32]);
      gload16(&BT[(size_t)(rg + srow) * 2048 + k0 + p * 32 + sseg], &Bpan[p][rg * 32]);
    }
    __syncthreads();

#pragma unroll
    for (int ks = 0; ks < 2; ks++) {
      bf16x8 af[4], bf[4];
#pragma unroll
      for (int i = 0; i < 4; i++)
        af[i] = *(const bf16x8*)&Apan[ks][(wm + i * 16 + l16) * 32 + quad * 8];
#pragma unroll
      for (int i = 0; i < 4; i++)
        bf[i] = *(const bf16x8*)&Bpan[ks][(wn + i * 16 + l16) * 32 + quad * 8];
#pragma unroll
      for (int mi = 0; mi < 4; mi++)
#pragma unroll
        for (int ni = 0; ni < 4; ni++)
          acc[mi][ni] = __builtin_amdgcn_mfma_f32_16x16x32_bf16(
              af[mi], bf[ni], acc[mi][ni], 0, 0, 0);
    }
  }

#pragma unroll
  for (int mi = 0; mi < 4; mi++)
#pragma unroll
    for (int ni = 0; ni < 4; ni++)
#pragma unroll
      for (int r = 0; r < 4; r++) {
        int row = m0 + wm + mi * 16 + quad * 4 + r;
        int col = c0 + wn + ni * 16 + l16;
        C[(size_t)row * ldC + col] = (__bf16)acc[mi][ni][r];
      }
}

// ---------------------------------------------------------------------------
// Final GEMM, pure-bf16 path, BK=64 panels: out fp32 = at bf16 @ WoT^T.
// ---------------------------------------------------------------------------
__global__ __launch_bounds__(256) void gemm_out_bt(
    const __bf16* __restrict__ A, const __bf16* __restrict__ BT,
    float* __restrict__ Cp)
{
  __shared__ __align__(16) __bf16 Apan[2][128 * 32];
  __shared__ __align__(16) __bf16 Bpan[2][128 * 32];
  const int tid = threadIdx.x, wave = tid >> 6, lane = tid & 63;
  const int quad = lane >> 4, l16 = lane & 15;
  const int n0 = blockIdx.x * 128, m0 = blockIdx.y * 128;
  const int wm = (wave >> 1) * 64, wn = (wave & 1) * 64;
  const int srow = lane >> 2, sseg = (lane & 3) * 8;

  f32x4 acc[4][4];
#pragma unroll
  for (int i = 0; i < 4; i++)
#pragma unroll
    for (int j = 0; j < 4; j++) acc[i][j] = (f32x4){0.f, 0.f, 0.f, 0.f};

  for (int k0 = 0; k0 < 2048; k0 += 64) {
    __syncthreads();
#pragma unroll
    for (int c = 0; c < 4; c++) {
      int idx = wave * 4 + c;
      int p = idx >> 3, rg = (idx & 7) * 16;
      gload16(&A[(size_t)(m0 + rg + srow) * 2048 + k0 + p * 32 + sseg], &Apan[p][rg * 32]);
      gload16(&BT[(size_t)(n0 + rg + srow) * 2048 + k0 + p * 32 + sseg], &Bpan[p][rg * 32]);
    }
    __syncthreads();

#pragma unroll
    for (int ks = 0; ks < 2; ks++) {
      bf16x8 af[4], bf[4];
#pragma unroll
      for (int i = 0; i < 4; i++)
        af[i] = *(const bf16x8*)&Apan[ks][(wm + i * 16 + l16) * 32 + quad * 8];
#pragma unroll
      for (int i = 0; i < 4; i++)
        bf[i] = *(const bf16x8*)&Bpan[ks][(wn + i * 16 + l16) * 32 + quad * 8];
#pragma unroll
      for (int mi = 0; mi < 4; mi++)
#pragma unroll
        for (int ni = 0; ni < 4; ni++)
          acc[mi][ni] = __builtin_amdgcn_mfma_f32_16x16x32_bf16(
              af[mi], bf[ni], acc[mi][ni], 0, 0, 0);
    }
  }

#pragma unroll
  for (int mi = 0; mi < 4; mi++)
#pragma unroll
    for (int ni = 0; ni < 4; ni++)
#pragma unroll
      for (int r = 0; r < 4; r++) {
        int row = m0 + wm + mi * 16 + quad * 4 + r;
        int col = n0 + wn + ni * 16 + l16;
        Cp[(size_t)row * 2048 + col] = acc[mi][ni][r];
      }
}

// ---------------------------------------------------------------------------
// Final GEMM, fallback (ws too small for WoT): round-7 kernel verbatim.
// ---------------------------------------------------------------------------
__global__ __launch_bounds__(256) void gemm_out_f32b(
    const __bf16* __restrict__ A, const float* __restrict__ B,
    float* __restrict__ Cp)
{
  __shared__ __align__(16) __bf16 Asl[128 * 32];
  __shared__ __align__(16) __bf16 BsT[128 * 32];
  const int tid = threadIdx.x, wave = tid >> 6, lane = tid & 63;
  const int quad = lane >> 4, l16 = lane & 15;
  const int n0 = blockIdx.x * 128, m0 = blockIdx.y * 128;
  const int wm = (wave >> 1) * 64, wn = (wave & 1) * 64;
  const int lrow = lane >> 2, lseg = (lane & 3) * 8;
  const int kg = (tid >> 5) * 4, ng = (tid & 31) * 4;

  f32x4 acc[4][4];
#pragma unroll
  for (int i = 0; i < 4; i++)
#pragma unroll
    for (int j = 0; j < 4; j++) acc[i][j] = (f32x4){0.f, 0.f, 0.f, 0.f};

  for (int k0 = 0; k0 < 2048; k0 += 32) {
    __syncthreads();
#pragma unroll
    for (int c = 0; c < 2; c++) {
      int ch = wave * 2 + c;
      gload16(&A[(size_t)(m0 + ch * 16 + lrow) * 2048 + k0 + lseg], &Asl[ch * 512]);
    }
    __bf16 h[4][4];
#pragma unroll
    for (int i = 0; i < 4; i++) {
      float4 w = *(const float4*)&B[(size_t)(k0 + kg + i) * 2048 + n0 + ng];
      h[i][0] = (__bf16)w.x; h[i][1] = (__bf16)w.y;
      h[i][2] = (__bf16)w.z; h[i][3] = (__bf16)w.w;
    }
#pragma unroll
    for (int j = 0; j < 4; j++) {
      int n = ng + j;
      int pb = ((kg >> 3) + (n >> 2)) & 3;
      __bf16 o4[4] = {h[0][j], h[1][j], h[2][j], h[3][j]};
      *(uint2*)&BsT[n * 32 + pb * 8 + (kg & 7)] = *(uint2*)o4;
    }
    __syncthreads();

    bf16x8 af[4], bf[4];
#pragma unroll
    for (int i = 0; i < 4; i++)
      af[i] = *(const bf16x8*)&Asl[(wm + i * 16 + l16) * 32 + quad * 8];
#pragma unroll
    for (int i = 0; i < 4; i++) {
      int n = wn + i * 16 + l16;
      int pb = (quad + (n >> 2)) & 3;
      bf[i] = *(const bf16x8*)&BsT[n * 32 + pb * 8];
    }
#pragma unroll
    for (int mi = 0; mi < 4; mi++)
#pragma unroll
      for (int ni = 0; ni < 4; ni++)
        acc[mi][ni] = __builtin_amdgcn_mfma_f32_16x16x32_bf16(
            af[mi], bf[ni], acc[mi][ni], 0, 0, 0);
  }

#pragma unroll
  for (int mi = 0; mi < 4; mi++)
#pragma unroll
    for (int ni = 0; ni < 4; ni++)
#pragma unroll
      for (int r = 0; r < 4; r++) {
        int row = m0 + wm + mi * 16 + quad * 4 + r;
        int col = n0 + wn + ni * 16 + l16;
        Cp[(size_t)row * 2048 + col] = acc[mi][ni][r];
      }
}

// ---------------------------------------------------------------------------
// MQA causal flash attention. ROUND 9: K and V^T staged via gload16 into
// 32-col LDS panels ([row][32], the proven GEMM fragment layout) — no VALU
// transpose, no staging writes through VGPRs. V^T comes pre-transposed from
// global (transpose_v). S^T trick + fixed-base softmax + l=P@ones retained.
// Pad keys (beyond 2047 / beyond qrow) get garbage-but-finite data, zeroed
// by the causal mask (last chunk of each q-tile always takes masked branch).
// IN-PLACE SAFE Q==O.
// ---------------------------------------------------------------------------
#define PR_LD 72

__global__ __launch_bounds__(256) void mqa_attn_mfma(
    const __bf16* Q, const __bf16* __restrict__ Km,
    const __bf16* __restrict__ VTm, __bf16* O)
{
  __shared__ __align__(16) __bf16 KsP[4][64 * 32];   // [d-panel][key][32d]
  __shared__ __align__(16) __bf16 VsP[2][128 * 32];  // [key-panel][d][32keys]
  __shared__ __align__(16) __bf16 Pr[4][32 * PR_LD];

  const int tid = threadIdx.x, wave = tid >> 6, lane = tid & 63;
  const int quad = lane >> 4, l16 = lane & 15;
  const int t = blockIdx.x >> 1, bat = blockIdx.x & 1;
  const int hg = blockIdx.y & 3, flip = blockIdx.y >> 2;
  const int qt = flip ? (63 - t) : t;
  const int h = hg * 4 + wave;
  const int q0 = qt * 32;
  const size_t qgrow = (size_t)bat * 2048 + q0;
  const float SCL2 = 0.08838834764831845f * 1.4426950408889634f;  // scale*log2e

  bf16x8 qf[2][4];
#pragma unroll
  for (int mi = 0; mi < 2; mi++)
#pragma unroll
    for (int ks = 0; ks < 4; ks++)
      qf[mi][ks] = *(const bf16x8*)(Q + (qgrow + mi * 16 + l16) * 2048 +
                                    h * 128 + ks * 32 + quad * 8);

  bf16x8 ones;
#pragma unroll
  for (int i = 0; i < 8; i++) ones[i] = (__bf16)1.0f;

  f32x4 oa[2][8];
#pragma unroll
  for (int mi = 0; mi < 2; mi++)
#pragma unroll
    for (int nt = 0; nt < 8; nt++) oa[mi][nt] = (f32x4){0.f, 0.f, 0.f, 0.f};
  f32x4 lacc[2];
  lacc[0] = (f32x4){0.f, 0.f, 0.f, 0.f};
  lacc[1] = (f32x4){0.f, 0.f, 0.f, 0.f};

  const __bf16* Kb  = Km  + (size_t)bat * 2048 * 128;
  const __bf16* VTb = VTm + (size_t)bat * 128 * 2048;
  const int qmax = q0 + 31;
  const int srow = lane >> 2, sseg = (lane & 3) * 8;
  const int vp = wave >> 1, vdb = (wave & 1) * 64;

  for (int sc = 0; sc <= qmax; sc += 64) {
    __syncthreads();
    // --- K panels: wave stages d-panel [wave]; per call 16 keys x 32 d ---
#pragma unroll
    for (int c = 0; c < 4; c++) {
      int kr = sc + c * 16 + srow; if (kr > 2047) kr = 2047;
      gload16(&Kb[(size_t)kr * 128 + wave * 32 + sseg], &KsP[wave][c * 512]);
    }
    // --- V^T panels: wave (p=w>>1, d-half (w&1)*64); 16 d x 32 keys/call ---
#pragma unroll
    for (int c = 0; c < 4; c++) {
      int d = vdb + c * 16 + srow;
      gload16(&VTb[(size_t)d * 2048 + sc + vp * 32 + sseg], &VsP[vp][(vdb + c * 16) * 32]);
    }
    __syncthreads();

    // --- S^T = K @ Q^T : reg r = S^T[key=kt*16+quad*4+r][qrow=l16(+16mi)] ---
    f32x4 sf[2][4];
#pragma unroll
    for (int mi = 0; mi < 2; mi++)
#pragma unroll
      for (int kt = 0; kt < 4; kt++) sf[mi][kt] = (f32x4){0.f, 0.f, 0.f, 0.f};
#pragma unroll
    for (int ks = 0; ks < 4; ks++)
#pragma unroll
      for (int kt = 0; kt < 4; kt++) {
        bf16x8 kf = *(const bf16x8*)&KsP[ks][(kt * 16 + l16) * 32 + quad * 8];
        sf[0][kt] = __builtin_amdgcn_mfma_f32_16x16x32_bf16(kf, qf[0][ks], sf[0][kt], 0, 0, 0);
        sf[1][kt] = __builtin_amdgcn_mfma_f32_16x16x32_bf16(kf, qf[1][ks], sf[1][kt], 0, 0, 0);
      }

    // --- P = exp2(S*SCL2), Pr[qrow][key] via b64 (4 contiguous keys/reg) ---
    __bf16* prw = Pr[wave];
    if (sc + 64 > q0) {  // uniform: only the diagonal chunk needs the mask
#pragma unroll
      for (int mi = 0; mi < 2; mi++) {
        int qrow = q0 + mi * 16 + l16;
#pragma unroll
        for (int kt = 0; kt < 4; kt++) {
          int kbase = sc + kt * 16 + quad * 4;
          __bf16 h4[4];
#pragma unroll
          for (int r = 0; r < 4; r++) {
            float p = (kbase + r <= qrow) ? exp2f(sf[mi][kt][r] * SCL2) : 0.f;
            h4[r] = (__bf16)p;
          }
          *(uint2*)&prw[(mi * 16 + l16) * PR_LD + kt * 16 + quad * 4] = *(uint2*)h4;
        }
      }
    } else {
#pragma unroll
      for (int mi = 0; mi < 2; mi++)
#pragma unroll
        for (int kt = 0; kt < 4; kt++) {
          __bf16 h4[4];
#pragma unroll
          for (int r = 0; r < 4; r++) h4[r] = (__bf16)exp2f(sf[mi][kt][r] * SCL2);
          *(uint2*)&prw[(mi * 16 + l16) * PR_LD + kt * 16 + quad * 4] = *(uint2*)h4;
        }
    }

    // --- O += P @ V ; l += P @ 1 ---
#pragma unroll
    for (int ks2 = 0; ks2 < 2; ks2++) {
      bf16x8 pf0 = *(const bf16x8*)&prw[(l16) * PR_LD + ks2 * 32 + quad * 8];
      bf16x8 pf1 = *(const bf16x8*)&prw[(16 + l16) * PR_LD + ks2 * 32 + quad * 8];
      lacc[0] = __builtin_amdgcn_mfma_f32_16x16x32_bf16(pf0, ones, lacc[0], 0, 0, 0);
      lacc[1] = __builtin_amdgcn_mfma_f32_16x16x32_bf16(pf1, ones, lacc[1], 0, 0, 0);
#pragma unroll
      for (int nt = 0; nt < 8; nt++) {
        bf16x8 vf = *(const bf16x8*)&VsP[ks2][(nt * 16 + l16) * 32 + quad * 8];
        oa[0][nt] = __builtin_amdgcn_mfma_f32_16x16x32_bf16(pf0, vf, oa[0][nt], 0, 0, 0);
        oa[1][nt] = __builtin_amdgcn_mfma_f32_16x16x32_bf16(pf1, vf, oa[1][nt], 0, 0, 0);
      }
    }
  }

  // epilogue: O[row] = oa / l   (l > 0: diagonal key always unmasked)
#pragma unroll
  for (int mi = 0; mi < 2; mi++)
#pragma unroll
    for (int r = 0; r < 4; r++) {
      float inv = 1.f / lacc[mi][r];
      size_t row = qgrow + mi * 16 + quad * 4 + r;
#pragma unroll
      for (int nt = 0; nt < 8; nt++)
        O[row * 2048 + h * 128 + nt * 16 + l16] = (__bf16)(oa[mi][nt][r] * inv);
    }
}

// ---------------------------------------------------------------------------
// Memory plan:
//   ws   : q / at (in-place) 16.78 MB | WoT 8.39 MB (if ws_size allows)
//   d_out: xb | WqT | WkT | WvT | k | v | vT  29.4 MB (dead before final GEMM)
// ---------------------------------------------------------------------------
extern "C" void kernel_launch(void* const* d_in, const int* in_sizes, int n_in,
                              void* d_out, int out_size, void* d_ws, size_t ws_size,
                              hipStream_t stream) {
  const float* x  = (const float*)d_in[0];
  const float* Wq = (const float*)d_in[1];
  const float* Wk = (const float*)d_in[2];
  const float* Wv = (const float*)d_in[3];
  const float* Wo = (const float*)d_in[4];
  float* out = (float*)d_out;

  __bf16* q   = (__bf16*)d_ws;
  __bf16* WoT = (__bf16*)((char*)d_ws + 16777216);
  const bool have_wot = ws_size >= (size_t)(16777216 + 8388608);

  char* ob = (char*)d_out;
  __bf16* xb  = (__bf16*)(ob);
  __bf16* WqT = (__bf16*)(ob + 16777216);
  __bf16* WkT = (__bf16*)(ob + 25165824);
  __bf16* WvT = (__bf16*)(ob + 25690112);
  __bf16* kb  = (__bf16*)(ob + 26214400);
  __bf16* vb  = (__bf16*)(ob + 27262976);
  __bf16* vT  = (__bf16*)(ob + 28311552);   // 1 MB + slack, ends < 29.4 MB

  dim3 blk(256);
  conv_bf16<<<4096, blk, 0, stream>>>(x, xb);
  transpose_w<<<dim3(32, 32), blk, 0, stream>>>(Wq, WqT, 2048, 2048);
  transpose_w<<<dim3(2, 32), blk, 0, stream>>>(Wk, WkT, 2048, 128);
  transpose_w<<<dim3(2, 32), blk, 0, stream>>>(Wv, WvT, 2048, 128);
  if (have_wot)
    transpose_w<<<dim3(32, 32), blk, 0, stream>>>(Wo, WoT, 2048, 2048);
  gemm_qkv<<<dim3(18, 32), blk, 0, stream>>>(xb, WqT, WkT, WvT, q, kb, vb);
  transpose_v<<<dim3(32, 2, 2), blk, 0, stream>>>(vb, vT);
  mqa_attn_mfma<<<dim3(64, 8, 1), blk, 0, stream>>>(q, kb, vT, q);
  if (have_wot)
    gemm_out_bt<<<dim3(16, 32), blk, 0, stream>>>(q, WoT, out);
  else
    gemm_out_f32b<<<dim3(16, 32), blk, 0, stream>>>(q, Wo, out);
}

// Round 10
// 305.512 us; speedup vs baseline: 1.0069x; 1.0069x over previous
//
#include <hip/hip_runtime.h>

typedef __bf16 bf16x8 __attribute__((ext_vector_type(8)));
typedef float f32x4 __attribute__((ext_vector_type(4)));

// Async global->LDS, 16B per lane. Global side: PER-LANE addresses (gather ok).
// LDS side: wave-uniform base + lane*16 (no padding within a call's 1 KB).
__device__ inline void gload16(const __bf16* g, __bf16* l) {
  __builtin_amdgcn_global_load_lds(
      (const __attribute__((address_space(1))) unsigned int*)g,
      (__attribute__((address_space(3))) unsigned int*)l, 16, 0, 0);
}

// ---------------------------------------------------------------------------
// Prep: fp32 -> bf16 elementwise (x). 8 elems/thread.
// ---------------------------------------------------------------------------
__global__ __launch_bounds__(256) void conv_bf16(
    const float* __restrict__ in, __bf16* __restrict__ out)
{
  size_t i = ((size_t)blockIdx.x * 256 + threadIdx.x) * 8;
  float4 a = *(const float4*)&in[i];
  float4 b = *(const float4*)&in[i + 4];
  bf16x8 h;
  h[0] = (__bf16)a.x; h[1] = (__bf16)a.y; h[2] = (__bf16)a.z; h[3] = (__bf16)a.w;
  h[4] = (__bf16)b.x; h[5] = (__bf16)b.y; h[6] = (__bf16)b.z; h[7] = (__bf16)b.w;
  *(bf16x8*)&out[i] = h;
}

// ---------------------------------------------------------------------------
// Prep: W fp32 [Kd][Nd] -> WT bf16 [Nd][Kd]. 64x64 LDS tile.
// ---------------------------------------------------------------------------
__global__ __launch_bounds__(256) void transpose_w(
    const float* __restrict__ W, __bf16* __restrict__ WT, int Kd, int Nd)
{
  __shared__ __bf16 Ts[64 * 72];
  const int tid = threadIdx.x;
  const int c0 = blockIdx.x * 64, r0 = blockIdx.y * 64;
#pragma unroll
  for (int i = 0; i < 4; i++) {
    int row = (tid >> 4) + i * 16, cv = (tid & 15) * 4;
    float4 w = *(const float4*)&W[(size_t)(r0 + row) * Nd + c0 + cv];
    Ts[(cv + 0) * 72 + row] = (__bf16)w.x;
    Ts[(cv + 1) * 72 + row] = (__bf16)w.y;
    Ts[(cv + 2) * 72 + row] = (__bf16)w.z;
    Ts[(cv + 3) * 72 + row] = (__bf16)w.w;
  }
  __syncthreads();
#pragma unroll
  for (int i = 0; i < 4; i++) {
    int n = (tid >> 4) + i * 16, kseg = (tid & 15) * 4;
    *(uint2*)&WT[(size_t)(c0 + n) * Kd + r0 + kseg] = *(uint2*)&Ts[n * 72 + kseg];
  }
}

// ---------------------------------------------------------------------------
// Prep: v bf16 [B*T][128] -> vT bf16 [B][128][T]. 64x64 tiles.
// ---------------------------------------------------------------------------
__global__ __launch_bounds__(256) void transpose_v(
    const __bf16* __restrict__ V, __bf16* __restrict__ VT)
{
  __shared__ __bf16 Ts[64 * 72];
  const int tid = threadIdx.x;
  const int t0 = blockIdx.x * 64, d0 = blockIdx.y * 64, bz = blockIdx.z;
#pragma unroll
  for (int i = 0; i < 4; i++) {
    int tr = (tid >> 4) + i * 16, dc = (tid & 15) * 4;
    union { uint2 u; __bf16 h[4]; } v;
    v.u = *(const uint2*)&V[(size_t)(bz * 2048 + t0 + tr) * 128 + d0 + dc];
    Ts[(dc + 0) * 72 + tr] = v.h[0];
    Ts[(dc + 1) * 72 + tr] = v.h[1];
    Ts[(dc + 2) * 72 + tr] = v.h[2];
    Ts[(dc + 3) * 72 + tr] = v.h[3];
  }
  __syncthreads();
#pragma unroll
  for (int i = 0; i < 4; i++) {
    int d = (tid >> 4) + i * 16, ts = (tid & 15) * 4;
    *(uint2*)&VT[(size_t)bz * 128 * 2048 + (size_t)(d0 + d) * 2048 + t0 + ts] =
        *(uint2*)&Ts[d * 72 + ts];
  }
}

// ---------------------------------------------------------------------------
// Fused q/k/v projection GEMM. ROUND 10: double-buffered async staging —
// chunk k+1's global_load_lds issued BEFORE computing chunk k, ONE barrier
// per iteration. 2x16 KB panels (32 KB total, unchanged).
// ---------------------------------------------------------------------------
__global__ __launch_bounds__(256) void gemm_qkv(
    const __bf16* __restrict__ A, const __bf16* __restrict__ WqT,
    const __bf16* __restrict__ WkT, const __bf16* __restrict__ WvT,
    __bf16* __restrict__ Cq, __bf16* __restrict__ Ck, __bf16* __restrict__ Cv)
{
  __shared__ __align__(16) __bf16 Apan[2][128 * 32];
  __shared__ __align__(16) __bf16 Bpan[2][128 * 32];
  const int tid = threadIdx.x, wave = tid >> 6, lane = tid & 63;
  const int quad = lane >> 4, l16 = lane & 15;
  const int nb = blockIdx.x, m0 = blockIdx.y * 128;
  const __bf16* BT; __bf16* C; int ldC, c0;
  if (nb < 16)       { BT = WqT + (size_t)nb * 128 * 2048; C = Cq; ldC = 2048; c0 = nb * 128; }
  else if (nb == 16) { BT = WkT; C = Ck; ldC = 128; c0 = 0; }
  else               { BT = WvT; C = Cv; ldC = 128; c0 = 0; }
  const int wm = (wave >> 1) * 64, wn = (wave & 1) * 64;
  const int srow = lane >> 2, sseg = (lane & 3) * 8;

  f32x4 acc[4][4];
#pragma unroll
  for (int i = 0; i < 4; i++)
#pragma unroll
    for (int j = 0; j < 4; j++) acc[i][j] = (f32x4){0.f, 0.f, 0.f, 0.f};

  // stage chunk at k0 into panel p (per wave: 2 A-calls + 2 B-calls)
#define QKV_STAGE(k0, p)                                                      \
  {                                                                           \
    _Pragma("unroll")                                                         \
    for (int c = 0; c < 2; c++) {                                             \
      int ch = wave * 2 + c;                                                  \
      gload16(&A[(size_t)(m0 + ch * 16 + srow) * 2048 + (k0) + sseg],         \
              &Apan[p][ch * 512]);                                            \
      gload16(&BT[(size_t)(ch * 16 + srow) * 2048 + (k0) + sseg],             \
              &Bpan[p][ch * 512]);                                            \
    }                                                                         \
  }

  QKV_STAGE(0, 0);
  int p = 0;
  for (int k0 = 0; k0 < 2048; k0 += 32) {
    __syncthreads();                  // panel p ready; old p^1 reads done
    if (k0 + 32 < 2048) QKV_STAGE(k0 + 32, p ^ 1);

    bf16x8 af[4], bf[4];
#pragma unroll
    for (int i = 0; i < 4; i++)
      af[i] = *(const bf16x8*)&Apan[p][(wm + i * 16 + l16) * 32 + quad * 8];
#pragma unroll
    for (int i = 0; i < 4; i++)
      bf[i] = *(const bf16x8*)&Bpan[p][(wn + i * 16 + l16) * 32 + quad * 8];
#pragma unroll
    for (int mi = 0; mi < 4; mi++)
#pragma unroll
      for (int ni = 0; ni < 4; ni++)
        acc[mi][ni] = __builtin_amdgcn_mfma_f32_16x16x32_bf16(
            af[mi], bf[ni], acc[mi][ni], 0, 0, 0);
    p ^= 1;
  }
#undef QKV_STAGE

#pragma unroll
  for (int mi = 0; mi < 4; mi++)
#pragma unroll
    for (int ni = 0; ni < 4; ni++)
#pragma unroll
      for (int r = 0; r < 4; r++) {
        int row = m0 + wm + mi * 16 + quad * 4 + r;
        int col = c0 + wn + ni * 16 + l16;
        C[(size_t)row * ldC + col] = (__bf16)acc[mi][ni][r];
      }
}

// ---------------------------------------------------------------------------
// Final GEMM, pure-bf16 path, double-buffered: out fp32 = at bf16 @ WoT^T.
// ---------------------------------------------------------------------------
__global__ __launch_bounds__(256) void gemm_out_bt(
    const __bf16* __restrict__ A, const __bf16* __restrict__ BT,
    float* __restrict__ Cp)
{
  __shared__ __align__(16) __bf16 Apan[2][128 * 32];
  __shared__ __align__(16) __bf16 Bpan[2][128 * 32];
  const int tid = threadIdx.x, wave = tid >> 6, lane = tid & 63;
  const int quad = lane >> 4, l16 = lane & 15;
  const int n0 = blockIdx.x * 128, m0 = blockIdx.y * 128;
  const int wm = (wave >> 1) * 64, wn = (wave & 1) * 64;
  const int srow = lane >> 2, sseg = (lane & 3) * 8;

  f32x4 acc[4][4];
#pragma unroll
  for (int i = 0; i < 4; i++)
#pragma unroll
    for (int j = 0; j < 4; j++) acc[i][j] = (f32x4){0.f, 0.f, 0.f, 0.f};

#define OUT_STAGE(k0, p)                                                      \
  {                                                                           \
    _Pragma("unroll")                                                         \
    for (int c = 0; c < 2; c++) {                                             \
      int ch = wave * 2 + c;                                                  \
      gload16(&A[(size_t)(m0 + ch * 16 + srow) * 2048 + (k0) + sseg],         \
              &Apan[p][ch * 512]);                                            \
      gload16(&BT[(size_t)(n0 + ch * 16 + srow) * 2048 + (k0) + sseg],        \
              &Bpan[p][ch * 512]);                                            \
    }                                                                         \
  }

  OUT_STAGE(0, 0);
  int p = 0;
  for (int k0 = 0; k0 < 2048; k0 += 32) {
    __syncthreads();
    if (k0 + 32 < 2048) OUT_STAGE(k0 + 32, p ^ 1);

    bf16x8 af[4], bf[4];
#pragma unroll
    for (int i = 0; i < 4; i++)
      af[i] = *(const bf16x8*)&Apan[p][(wm + i * 16 + l16) * 32 + quad * 8];
#pragma unroll
    for (int i = 0; i < 4; i++)
      bf[i] = *(const bf16x8*)&Bpan[p][(wn + i * 16 + l16) * 32 + quad * 8];
#pragma unroll
    for (int mi = 0; mi < 4; mi++)
#pragma unroll
      for (int ni = 0; ni < 4; ni++)
        acc[mi][ni] = __builtin_amdgcn_mfma_f32_16x16x32_bf16(
            af[mi], bf[ni], acc[mi][ni], 0, 0, 0);
    p ^= 1;
  }
#undef OUT_STAGE

#pragma unroll
  for (int mi = 0; mi < 4; mi++)
#pragma unroll
    for (int ni = 0; ni < 4; ni++)
#pragma unroll
      for (int r = 0; r < 4; r++) {
        int row = m0 + wm + mi * 16 + quad * 4 + r;
        int col = n0 + wn + ni * 16 + l16;
        Cp[(size_t)row * 2048 + col] = acc[mi][ni][r];
      }
}

// ---------------------------------------------------------------------------
// Final GEMM, fallback (ws too small for WoT): round-7 kernel verbatim.
// ---------------------------------------------------------------------------
__global__ __launch_bounds__(256) void gemm_out_f32b(
    const __bf16* __restrict__ A, const float* __restrict__ B,
    float* __restrict__ Cp)
{
  __shared__ __align__(16) __bf16 Asl[128 * 32];
  __shared__ __align__(16) __bf16 BsT[128 * 32];
  const int tid = threadIdx.x, wave = tid >> 6, lane = tid & 63;
  const int quad = lane >> 4, l16 = lane & 15;
  const int n0 = blockIdx.x * 128, m0 = blockIdx.y * 128;
  const int wm = (wave >> 1) * 64, wn = (wave & 1) * 64;
  const int lrow = lane >> 2, lseg = (lane & 3) * 8;
  const int kg = (tid >> 5) * 4, ng = (tid & 31) * 4;

  f32x4 acc[4][4];
#pragma unroll
  for (int i = 0; i < 4; i++)
#pragma unroll
    for (int j = 0; j < 4; j++) acc[i][j] = (f32x4){0.f, 0.f, 0.f, 0.f};

  for (int k0 = 0; k0 < 2048; k0 += 32) {
    __syncthreads();
#pragma unroll
    for (int c = 0; c < 2; c++) {
      int ch = wave * 2 + c;
      gload16(&A[(size_t)(m0 + ch * 16 + lrow) * 2048 + k0 + lseg], &Asl[ch * 512]);
    }
    __bf16 h[4][4];
#pragma unroll
    for (int i = 0; i < 4; i++) {
      float4 w = *(const float4*)&B[(size_t)(k0 + kg + i) * 2048 + n0 + ng];
      h[i][0] = (__bf16)w.x; h[i][1] = (__bf16)w.y;
      h[i][2] = (__bf16)w.z; h[i][3] = (__bf16)w.w;
    }
#pragma unroll
    for (int j = 0; j < 4; j++) {
      int n = ng + j;
      int pb = ((kg >> 3) + (n >> 2)) & 3;
      __bf16 o4[4] = {h[0][j], h[1][j], h[2][j], h[3][j]};
      *(uint2*)&BsT[n * 32 + pb * 8 + (kg & 7)] = *(uint2*)o4;
    }
    __syncthreads();

    bf16x8 af[4], bf[4];
#pragma unroll
    for (int i = 0; i < 4; i++)
      af[i] = *(const bf16x8*)&Asl[(wm + i * 16 + l16) * 32 + quad * 8];
#pragma unroll
    for (int i = 0; i < 4; i++) {
      int n = wn + i * 16 + l16;
      int pb = (quad + (n >> 2)) & 3;
      bf[i] = *(const bf16x8*)&BsT[n * 32 + pb * 8];
    }
#pragma unroll
    for (int mi = 0; mi < 4; mi++)
#pragma unroll
      for (int ni = 0; ni < 4; ni++)
        acc[mi][ni] = __builtin_amdgcn_mfma_f32_16x16x32_bf16(
            af[mi], bf[ni], acc[mi][ni], 0, 0, 0);
  }

#pragma unroll
  for (int mi = 0; mi < 4; mi++)
#pragma unroll
    for (int ni = 0; ni < 4; ni++)
#pragma unroll
      for (int r = 0; r < 4; r++) {
        int row = m0 + wm + mi * 16 + quad * 4 + r;
        int col = n0 + wn + ni * 16 + l16;
        Cp[(size_t)row * 2048 + col] = acc[mi][ni][r];
      }
}

// ---------------------------------------------------------------------------
// MQA causal flash attention (unchanged from round 9). gload16 panel staging,
// S^T trick, fixed-base softmax, l = P @ ones. IN-PLACE SAFE Q==O.
// ---------------------------------------------------------------------------
#define PR_LD 72

__global__ __launch_bounds__(256) void mqa_attn_mfma(
    const __bf16* Q, const __bf16* __restrict__ Km,
    const __bf16* __restrict__ VTm, __bf16* O)
{
  __shared__ __align__(16) __bf16 KsP[4][64 * 32];   // [d-panel][key][32d]
  __shared__ __align__(16) __bf16 VsP[2][128 * 32];  // [key-panel][d][32keys]
  __shared__ __align__(16) __bf16 Pr[4][32 * PR_LD];

  const int tid = threadIdx.x, wave = tid >> 6, lane = tid & 63;
  const int quad = lane >> 4, l16 = lane & 15;
  const int t = blockIdx.x >> 1, bat = blockIdx.x & 1;
  const int hg = blockIdx.y & 3, flip = blockIdx.y >> 2;
  const int qt = flip ? (63 - t) : t;
  const int h = hg * 4 + wave;
  const int q0 = qt * 32;
  const size_t qgrow = (size_t)bat * 2048 + q0;
  const float SCL2 = 0.08838834764831845f * 1.4426950408889634f;  // scale*log2e

  bf16x8 qf[2][4];
#pragma unroll
  for (int mi = 0; mi < 2; mi++)
#pragma unroll
    for (int ks = 0; ks < 4; ks++)
      qf[mi][ks] = *(const bf16x8*)(Q + (qgrow + mi * 16 + l16) * 2048 +
                                    h * 128 + ks * 32 + quad * 8);

  bf16x8 ones;
#pragma unroll
  for (int i = 0; i < 8; i++) ones[i] = (__bf16)1.0f;

  f32x4 oa[2][8];
#pragma unroll
  for (int mi = 0; mi < 2; mi++)
#pragma unroll
    for (int nt = 0; nt < 8; nt++) oa[mi][nt] = (f32x4){0.f, 0.f, 0.f, 0.f};
  f32x4 lacc[2];
  lacc[0] = (f32x4){0.f, 0.f, 0.f, 0.f};
  lacc[1] = (f32x4){0.f, 0.f, 0.f, 0.f};

  const __bf16* Kb  = Km  + (size_t)bat * 2048 * 128;
  const __bf16* VTb = VTm + (size_t)bat * 128 * 2048;
  const int qmax = q0 + 31;
  const int srow = lane >> 2, sseg = (lane & 3) * 8;
  const int vp = wave >> 1, vdb = (wave & 1) * 64;

  for (int sc = 0; sc <= qmax; sc += 64) {
    __syncthreads();
#pragma unroll
    for (int c = 0; c < 4; c++) {
      int kr = sc + c * 16 + srow; if (kr > 2047) kr = 2047;
      gload16(&Kb[(size_t)kr * 128 + wave * 32 + sseg], &KsP[wave][c * 512]);
    }
#pragma unroll
    for (int c = 0; c < 4; c++) {
      int d = vdb + c * 16 + srow;
      gload16(&VTb[(size_t)d * 2048 + sc + vp * 32 + sseg], &VsP[vp][(vdb + c * 16) * 32]);
    }
    __syncthreads();

    f32x4 sf[2][4];
#pragma unroll
    for (int mi = 0; mi < 2; mi++)
#pragma unroll
      for (int kt = 0; kt < 4; kt++) sf[mi][kt] = (f32x4){0.f, 0.f, 0.f, 0.f};
#pragma unroll
    for (int ks = 0; ks < 4; ks++)
#pragma unroll
      for (int kt = 0; kt < 4; kt++) {
        bf16x8 kf = *(const bf16x8*)&KsP[ks][(kt * 16 + l16) * 32 + quad * 8];
        sf[0][kt] = __builtin_amdgcn_mfma_f32_16x16x32_bf16(kf, qf[0][ks], sf[0][kt], 0, 0, 0);
        sf[1][kt] = __builtin_amdgcn_mfma_f32_16x16x32_bf16(kf, qf[1][ks], sf[1][kt], 0, 0, 0);
      }

    __bf16* prw = Pr[wave];
    if (sc + 64 > q0) {
#pragma unroll
      for (int mi = 0; mi < 2; mi++) {
        int qrow = q0 + mi * 16 + l16;
#pragma unroll
        for (int kt = 0; kt < 4; kt++) {
          int kbase = sc + kt * 16 + quad * 4;
          __bf16 h4[4];
#pragma unroll
          for (int r = 0; r < 4; r++) {
            float p = (kbase + r <= qrow) ? exp2f(sf[mi][kt][r] * SCL2) : 0.f;
            h4[r] = (__bf16)p;
          }
          *(uint2*)&prw[(mi * 16 + l16) * PR_LD + kt * 16 + quad * 4] = *(uint2*)h4;
        }
      }
    } else {
#pragma unroll
      for (int mi = 0; mi < 2; mi++)
#pragma unroll
        for (int kt = 0; kt < 4; kt++) {
          __bf16 h4[4];
#pragma unroll
          for (int r = 0; r < 4; r++) h4[r] = (__bf16)exp2f(sf[mi][kt][r] * SCL2);
          *(uint2*)&prw[(mi * 16 + l16) * PR_LD + kt * 16 + quad * 4] = *(uint2*)h4;
        }
    }

#pragma unroll
    for (int ks2 = 0; ks2 < 2; ks2++) {
      bf16x8 pf0 = *(const bf16x8*)&prw[(l16) * PR_LD + ks2 * 32 + quad * 8];
      bf16x8 pf1 = *(const bf16x8*)&prw[(16 + l16) * PR_LD + ks2 * 32 + quad * 8];
      lacc[0] = __builtin_amdgcn_mfma_f32_16x16x32_bf16(pf0, ones, lacc[0], 0, 0, 0);
      lacc[1] = __builtin_amdgcn_mfma_f32_16x16x32_bf16(pf1, ones, lacc[1], 0, 0, 0);
#pragma unroll
      for (int nt = 0; nt < 8; nt++) {
        bf16x8 vf = *(const bf16x8*)&VsP[ks2][(nt * 16 + l16) * 32 + quad * 8];
        oa[0][nt] = __builtin_amdgcn_mfma_f32_16x16x32_bf16(pf0, vf, oa[0][nt], 0, 0, 0);
        oa[1][nt] = __builtin_amdgcn_mfma_f32_16x16x32_bf16(pf1, vf, oa[1][nt], 0, 0, 0);
      }
    }
  }

#pragma unroll
  for (int mi = 0; mi < 2; mi++)
#pragma unroll
    for (int r = 0; r < 4; r++) {
      float inv = 1.f / lacc[mi][r];
      size_t row = qgrow + mi * 16 + quad * 4 + r;
#pragma unroll
      for (int nt = 0; nt < 8; nt++)
        O[row * 2048 + h * 128 + nt * 16 + l16] = (__bf16)(oa[mi][nt][r] * inv);
    }
}

// ---------------------------------------------------------------------------
// Memory plan:
//   ws   : q / at (in-place) 16.78 MB | WoT 8.39 MB (if ws_size allows)
//   d_out: xb | WqT | WkT | WvT | k | v | vT  29.4 MB (dead before final GEMM)
// ---------------------------------------------------------------------------
extern "C" void kernel_launch(void* const* d_in, const int* in_sizes, int n_in,
                              void* d_out, int out_size, void* d_ws, size_t ws_size,
                              hipStream_t stream) {
  const float* x  = (const float*)d_in[0];
  const float* Wq = (const float*)d_in[1];
  const float* Wk = (const float*)d_in[2];
  const float* Wv = (const float*)d_in[3];
  const float* Wo = (const float*)d_in[4];
  float* out = (float*)d_out;

  __bf16* q   = (__bf16*)d_ws;
  __bf16* WoT = (__bf16*)((char*)d_ws + 16777216);
  const bool have_wot = ws_size >= (size_t)(16777216 + 8388608);

  char* ob = (char*)d_out;
  __bf16* xb  = (__bf16*)(ob);
  __bf16* WqT = (__bf16*)(ob + 16777216);
  __bf16* WkT = (__bf16*)(ob + 25165824);
  __bf16* WvT = (__bf16*)(ob + 25690112);
  __bf16* kb  = (__bf16*)(ob + 26214400);
  __bf16* vb  = (__bf16*)(ob + 27262976);
  __bf16* vT  = (__bf16*)(ob + 28311552);

  dim3 blk(256);
  conv_bf16<<<4096, blk, 0, stream>>>(x, xb);
  transpose_w<<<dim3(32, 32), blk, 0, stream>>>(Wq, WqT, 2048, 2048);
  transpose_w<<<dim3(2, 32), blk, 0, stream>>>(Wk, WkT, 2048, 128);
  transpose_w<<<dim3(2, 32), blk, 0, stream>>>(Wv, WvT, 2048, 128);
  if (have_wot)
    transpose_w<<<dim3(32, 32), blk, 0, stream>>>(Wo, WoT, 2048, 2048);
  gemm_qkv<<<dim3(18, 32), blk, 0, stream>>>(xb, WqT, WkT, WvT, q, kb, vb);
  transpose_v<<<dim3(32, 2, 2), blk, 0, stream>>>(vb, vT);
  mqa_attn_mfma<<<dim3(64, 8, 1), blk, 0, stream>>>(q, kb, vT, q);
  if (have_wot)
    gemm_out_bt<<<dim3(16, 32), blk, 0, stream>>>(q, WoT, out);
  else
    gemm_out_f32b<<<dim3(16, 32), blk, 0, stream>>>(q, Wo, out);
}